// Round 6
// baseline (89.263 us; speedup 1.0000x reference)
//
#include <hip/hip_runtime.h>

// FFMCell combine: out = state * exp((-|a| + i*b) * j) + x, elementwise over
// [T=4096, TRACE=64, CTX=64]; third output = j + i (per-t ints, stored as f32).
// R1-R5 all ~80us with VGPR=32: compiler serializes trips (~4KB in flight per
// wave) -> latency-bound at 53% of achievable HBM BW. R6: no loop, 4 items per
// thread, ALL 16 stream loads issued before any compute, pinned with
// sched_barrier(0). 16KB in flight per wave.

typedef float f32x4 __attribute__((ext_vector_type(4)));

constexpr int T_DIM  = 4096;
constexpr int N      = T_DIM * 64 * 64;      // 16,777,216 elements per array
constexpr int N4     = N / 4;                // 4,194,304 float4 items
constexpr int GRID   = 4096;
constexpr int BLOCK  = 256;
constexpr int STRIDE = GRID * BLOCK;         // 1,048,576 float4 items
constexpr int ITEMS  = N4 / STRIDE;          // 4, exact

__global__ __launch_bounds__(BLOCK) void ffm_kernel(
    const float* __restrict__ a,
    const float* __restrict__ b,
    const float* __restrict__ s_re,
    const float* __restrict__ s_im,
    const float* __restrict__ x_re,
    const float* __restrict__ x_im,
    const int*   __restrict__ iv,
    const int*   __restrict__ jv,
    float* __restrict__ out)
{
    const int gtid = blockIdx.x * blockDim.x + threadIdx.x;

    // Third output: (j + i) as float, T elements at offset 2*N.
    if (gtid < T_DIM) {
        out[2 * N + gtid] = (float)(jv[gtid] + iv[gtid]);
    }

    // Per-thread invariants: items are STRIDE apart = 1024 full t-planes, so
    // (m, c4) never change; t advances by 1024 per item.
    const int c4 = (gtid & 15) << 2;       // ctx offset of this float4
    const int m  = (gtid >> 4) & 63;       // trace index
    const int t0 = gtid >> 10;             // starting t (0..1023)

    const float am = fabsf(a[m]);
    const f32x4 bv = *reinterpret_cast<const f32x4*>(b + c4);

    // ---- Issue phase: all 17 loads before any compute. ----
    float tj[ITEMS];
    #pragma unroll
    for (int i = 0; i < ITEMS; ++i) {
        tj[i] = (float)jv[t0 + (i << 10)];
    }

    f32x4 sr[ITEMS], si[ITEMS], xr[ITEMS], xi[ITEMS];
    #pragma unroll
    for (int i = 0; i < ITEMS; ++i) {
        const int base = (gtid + i * STRIDE) << 2;   // element offset
        sr[i] = *reinterpret_cast<const f32x4*>(s_re + base);
        si[i] = *reinterpret_cast<const f32x4*>(s_im + base);
        xr[i] = *reinterpret_cast<const f32x4*>(x_re + base);
        xi[i] = *reinterpret_cast<const f32x4*>(x_im + base);
    }

    // Pin: nothing above sinks below, nothing below hoists above. The first
    // s_waitcnt the compiler inserts lands AFTER all 16 loads are in flight.
    __builtin_amdgcn_sched_barrier(0);

    // ---- Compute + store phase. ----
    #pragma unroll
    for (int i = 0; i < ITEMS; ++i) {
        const float decay = __expf(-am * tj[i]);
        f32x4 orv, oiv;
        #pragma unroll
        for (int k = 0; k < 4; ++k) {
            float s, c;
            __sincosf(bv[k] * tj[i], &s, &c);
            const float gre = decay * c;
            const float gim = decay * s;
            orv[k] = fmaf(sr[i][k], gre, fmaf(-si[i][k], gim, xr[i][k]));
            oiv[k] = fmaf(sr[i][k], gim, fmaf( si[i][k], gre, xi[i][k]));
        }
        const int base = (gtid + i * STRIDE) << 2;
        *reinterpret_cast<f32x4*>(out + base)     = orv;
        *reinterpret_cast<f32x4*>(out + N + base) = oiv;
    }
}

extern "C" void kernel_launch(void* const* d_in, const int* in_sizes, int n_in,
                              void* d_out, int out_size, void* d_ws, size_t ws_size,
                              hipStream_t stream) {
    const float* a    = (const float*)d_in[0];
    const float* b    = (const float*)d_in[1];
    const float* s_re = (const float*)d_in[2];
    const float* s_im = (const float*)d_in[3];
    const float* x_re = (const float*)d_in[4];
    const float* x_im = (const float*)d_in[5];
    const int*   iv   = (const int*)d_in[6];
    const int*   jv   = (const int*)d_in[7];
    float* out = (float*)d_out;

    ffm_kernel<<<GRID, BLOCK, 0, stream>>>(a, b, s_re, s_im, x_re, x_im, iv, jv, out);
}

// Round 7
// 82.029 us; speedup vs baseline: 1.0882x; 1.0882x over previous
//
#include <hip/hip_runtime.h>

// FFMCell combine: out = state * exp((-|a| + i*b) * j) + x over [4096,64,64];
// third output = j + i. R1-R6 plateau 78-90us: register-based ILP is defeated
// by the allocator every time (VGPR stays 32-48). R7: global_load_lds deep
// pipeline (m201/m218 pattern) -- per-wave private double-buffered LDS slab,
// counted vmcnt (never 0 in loop), in-flight bytes decoupled from VGPRs.

typedef float f32x4 __attribute__((ext_vector_type(4)));

constexpr int T_DIM = 4096;
constexpr int N     = T_DIM * 64 * 64;      // 16,777,216 floats per array
constexpr int N4    = N / 4;
constexpr int GRID  = 2048;
constexpr int BLOCK = 256;
constexpr int WPB   = BLOCK / 64;           // 4 waves/block
constexpr int NW    = GRID * WPB;           // 8192 waves
constexpr int KMAX  = (N4 / 64) / NW;       // 8 chunks per wave (exact)

__device__ __forceinline__ void gll16(const float* g, const float* l) {
    // global -> LDS async DMA, 16B/lane; LDS dest = uniform base + lane*16.
    __builtin_amdgcn_global_load_lds(
        (const __attribute__((address_space(1))) unsigned int*)g,
        (__attribute__((address_space(3))) unsigned int*)l, 16, 0, 0);
}

__global__ __launch_bounds__(BLOCK) void ffm_kernel(
    const float* __restrict__ a,
    const float* __restrict__ b,
    const float* __restrict__ s_re,
    const float* __restrict__ s_im,
    const float* __restrict__ x_re,
    const float* __restrict__ x_im,
    const int*   __restrict__ iv,
    const int*   __restrict__ jv,
    float* __restrict__ out)
{
    // [wave][buf][stream: sr,si,xr,xi][256 floats = 64 lanes x 4]
    __shared__ __align__(16) float slab[WPB][2][4][256];

    const int tid  = threadIdx.x;
    const int wave = tid >> 6;
    const int lane = tid & 63;
    const int w    = blockIdx.x * WPB + wave;    // global wave id, 0..8191
    const int gtid = blockIdx.x * BLOCK + tid;

    // Third output: (j + i) as float.
    if (gtid < T_DIM) {
        out[2 * N + gtid] = (float)(jv[gtid] + iv[gtid]);
    }

    // Chunk c_k = w + k*8192 covers floats [256*c, 256*c+256); lane owns 4.
    // 256*8192 = 2,097,152 = 0 mod 4096 -> (m, ctx) are chunk-invariant.
    const int   m  = ((w << 2) + (lane >> 4)) & 63;
    float am = fabsf(a[m]);
    const int   c4 = (lane & 15) << 2;
    float b0 = b[c4], b1 = b[c4 + 1], b2 = b[c4 + 2], b3 = b[c4 + 3];

    float tjv[KMAX];
    #pragma unroll
    for (int k = 0; k < KMAX; ++k) {
        tjv[k] = (float)jv[(w >> 4) + (k << 9)];   // t = chunk>>4, wave-uniform
    }

    // Pin invariant values into registers BEFORE the pipeline so no compiler
    // vmem/waitcnt lands inside the loop; fence stops the j+i store sinking.
    asm volatile("" : "+v"(am), "+v"(b0), "+v"(b1), "+v"(b2), "+v"(b3),
                      "+v"(tjv[0]), "+v"(tjv[1]), "+v"(tjv[2]), "+v"(tjv[3]),
                      "+v"(tjv[4]), "+v"(tjv[5]), "+v"(tjv[6]), "+v"(tjv[7]));
    asm volatile("" ::: "memory");

    const int lane4 = lane << 2;

    // Prologue: stage chunks 0 and 1 (4 gll each, in-order).
    {
        const int f0 = (w << 8) + lane4;                 // chunk 0
        gll16(s_re + f0, &slab[wave][0][0][0]);
        gll16(s_im + f0, &slab[wave][0][1][0]);
        gll16(x_re + f0, &slab[wave][0][2][0]);
        gll16(x_im + f0, &slab[wave][0][3][0]);
        const int f1 = ((w + (1 << 13)) << 8) + lane4;   // chunk 1
        gll16(s_re + f1, &slab[wave][1][0][0]);
        gll16(s_im + f1, &slab[wave][1][1][0]);
        gll16(x_re + f1, &slab[wave][1][2][0]);
        gll16(x_im + f1, &slab[wave][1][3][0]);
    }

    #pragma unroll
    for (int k = 0; k < KMAX; ++k) {
        const int buf = k & 1;

        // Counted wait: oldest chunk's 4 loads retired; newer ops (next
        // chunk's 4 loads + up to 2x2 stores) stay in flight. vmem issue
        // order: L0 L1 | L2 St0 | L3 St1 | ... -> newer-than-Lk budget:
        //   k=0: 4 (L1);  k=1: 6 (L2,St0);  k=2..6: 8 (St,L,St);  k=7: 4.
        if      (k == 0) asm volatile("s_waitcnt vmcnt(4)" ::: "memory");
        else if (k == 1) asm volatile("s_waitcnt vmcnt(6)" ::: "memory");
        else if (k <= 6) asm volatile("s_waitcnt vmcnt(8)" ::: "memory");
        else             asm volatile("s_waitcnt vmcnt(4)" ::: "memory");

        const f32x4 sr = *(const f32x4*)&slab[wave][buf][0][lane4];
        const f32x4 si = *(const f32x4*)&slab[wave][buf][1][lane4];
        const f32x4 xr = *(const f32x4*)&slab[wave][buf][2][lane4];
        const f32x4 xi = *(const f32x4*)&slab[wave][buf][3][lane4];

        // Data must be in registers before we overwrite this buffer.
        asm volatile("s_waitcnt lgkmcnt(0)" ::: "memory");

        if (k + 2 < KMAX) {
            const int fn = ((w + ((k + 2) << 13)) << 8) + lane4;
            gll16(s_re + fn, &slab[wave][buf][0][0]);
            gll16(s_im + fn, &slab[wave][buf][1][0]);
            gll16(x_re + fn, &slab[wave][buf][2][0]);
            gll16(x_im + fn, &slab[wave][buf][3][0]);
        }

        const float tj    = tjv[k];
        const float decay = __expf(-am * tj);
        float bb[4] = {b0, b1, b2, b3};
        f32x4 orv, oiv;
        #pragma unroll
        for (int q = 0; q < 4; ++q) {
            float s, c;
            __sincosf(bb[q] * tj, &s, &c);
            const float gre = decay * c;
            const float gim = decay * s;
            orv[q] = fmaf(sr[q], gre, fmaf(-si[q], gim, xr[q]));
            oiv[q] = fmaf(sr[q], gim, fmaf( si[q], gre, xi[q]));
        }

        const int f0 = ((w + (k << 13)) << 8) + lane4;
        *(f32x4*)(out + f0)     = orv;
        *(f32x4*)(out + N + f0) = oiv;
    }
}

extern "C" void kernel_launch(void* const* d_in, const int* in_sizes, int n_in,
                              void* d_out, int out_size, void* d_ws, size_t ws_size,
                              hipStream_t stream) {
    const float* a    = (const float*)d_in[0];
    const float* b    = (const float*)d_in[1];
    const float* s_re = (const float*)d_in[2];
    const float* s_im = (const float*)d_in[3];
    const float* x_re = (const float*)d_in[4];
    const float* x_im = (const float*)d_in[5];
    const int*   iv   = (const int*)d_in[6];
    const int*   jv   = (const int*)d_in[7];
    float* out = (float*)d_out;

    ffm_kernel<<<GRID, BLOCK, 0, stream>>>(a, b, s_re, s_im, x_re, x_im, iv, jv, out);
}

// Round 8
// 67.827 us; speedup vs baseline: 1.3160x; 1.2094x over previous
//
#include <hip/hip_runtime.h>

// FFMCell combine: out = state * exp((-|a| + i*b) * j) + x over [4096,64,64];
// third output = j + i. R1-R7 plateau 78-90us at ~4.9 TB/s combined fabric
// throughput; all ILP/in-flight levers null. R8: change the TRAFFIC instead --
// non-temporal stores on the DENSE layout (R1-style 16B/lane contiguous, full
// line density) so the 134MB output stream bypasses L2/L3 and stops evicting
// the 268MB input set; steady-state FETCH_SIZE should fall well below 134MB.

typedef float f32x4 __attribute__((ext_vector_type(4)));

constexpr int T_DIM  = 4096;
constexpr int N      = T_DIM * 64 * 64;      // 16,777,216 elements per array
constexpr int N4     = N / 4;                // 4,194,304 float4 items
constexpr int GRID   = 2048;
constexpr int BLOCK  = 256;
constexpr int STRIDE = GRID * BLOCK;         // 524,288 float4 items
constexpr int TRIPS  = N4 / STRIDE;          // 8, exact
constexpr int T_STEP = STRIDE >> 10;         // 512 t-planes per trip

__global__ __launch_bounds__(BLOCK, 8) void ffm_kernel(
    const float* __restrict__ a,
    const float* __restrict__ b,
    const float* __restrict__ s_re,
    const float* __restrict__ s_im,
    const float* __restrict__ x_re,
    const float* __restrict__ x_im,
    const int*   __restrict__ iv,
    const int*   __restrict__ jv,
    float* __restrict__ out)
{
    const int gtid = blockIdx.x * blockDim.x + threadIdx.x;

    // Third output: (j + i) as float, T elements at offset 2*N.
    if (gtid < T_DIM) {
        out[2 * N + gtid] = (float)(jv[gtid] + iv[gtid]);
    }

    // Per-thread invariants: trip stride is 512 full t-planes, so (m, c4)
    // never change across trips; only t advances by T_STEP.
    const int c4 = (gtid & 15) << 2;       // ctx offset of this float4
    const int m  = (gtid >> 4) & 63;       // trace index
    const int t0 = gtid >> 10;             // starting t (0..511)

    const float am = fabsf(a[m]);
    const f32x4 bv = *reinterpret_cast<const f32x4*>(b + c4);

    #pragma unroll
    for (int trip = 0; trip < TRIPS; ++trip) {
        const int base = (gtid + trip * STRIDE) << 2;   // element offset
        const float tj = (float)jv[t0 + trip * T_STEP];

        const f32x4 sr = *reinterpret_cast<const f32x4*>(s_re + base);
        const f32x4 si = *reinterpret_cast<const f32x4*>(s_im + base);
        const f32x4 xr = *reinterpret_cast<const f32x4*>(x_re + base);
        const f32x4 xi = *reinterpret_cast<const f32x4*>(x_im + base);

        const float decay = __expf(-am * tj);
        f32x4 orv, oiv;
        #pragma unroll
        for (int k = 0; k < 4; ++k) {
            float s, c;
            __sincosf(bv[k] * tj, &s, &c);
            const float gre = decay * c;
            const float gim = decay * s;
            orv[k] = fmaf(sr[k], gre, fmaf(-si[k], gim, xr[k]));
            oiv[k] = fmaf(sr[k], gim, fmaf( si[k], gre, xi[k]));
        }

        // Dense full-line non-temporal stores: bypass cache fill so the
        // output stream doesn't evict the input working set from L3.
        __builtin_nontemporal_store(orv, reinterpret_cast<f32x4*>(out + base));
        __builtin_nontemporal_store(oiv, reinterpret_cast<f32x4*>(out + N + base));
    }
}

extern "C" void kernel_launch(void* const* d_in, const int* in_sizes, int n_in,
                              void* d_out, int out_size, void* d_ws, size_t ws_size,
                              hipStream_t stream) {
    const float* a    = (const float*)d_in[0];
    const float* b    = (const float*)d_in[1];
    const float* s_re = (const float*)d_in[2];
    const float* s_im = (const float*)d_in[3];
    const float* x_re = (const float*)d_in[4];
    const float* x_im = (const float*)d_in[5];
    const int*   iv   = (const int*)d_in[6];
    const int*   jv   = (const int*)d_in[7];
    float* out = (float*)d_out;

    ffm_kernel<<<GRID, BLOCK, 0, stream>>>(a, b, s_re, s_im, x_re, x_im, iv, jv, out);
}

// Round 10
// 66.908 us; speedup vs baseline: 1.3341x; 1.0137x over previous
//
#include <hip/hip_runtime.h>

// FFMCell combine: out = state * exp((-|a| + i*b) * j) + x over [4096,64,64];
// third output = j + i. R8 (dense + builtin nt stores) = 67.8us, 3.95 TB/s
// HBM. R9's asm sc0/sc1 store corrupted output -> reverted to builtin nt.
// R10: test read-side in-flight cleanly -- 2-trip load batches pinned with a
// data-dependent asm fence (IR can't sink loads across a "+v" use), keeping
// VGPR<=64 so all 32 waves/CU stay resident. 8KB in flight per wave at the
// stall point (2x R8).

typedef float f32x4 __attribute__((ext_vector_type(4)));

constexpr int T_DIM  = 4096;
constexpr int N      = T_DIM * 64 * 64;      // 16,777,216 elements per array
constexpr int N4     = N / 4;                // 4,194,304 float4 items
constexpr int GRID   = 2048;
constexpr int BLOCK  = 256;
constexpr int STRIDE = GRID * BLOCK;         // 524,288 float4 items
constexpr int TRIPS  = N4 / STRIDE;          // 8, exact
constexpr int T_STEP = STRIDE >> 10;         // 512 t-planes per trip

__global__ __launch_bounds__(BLOCK, 8) void ffm_kernel(
    const float* __restrict__ a,
    const float* __restrict__ b,
    const float* __restrict__ s_re,
    const float* __restrict__ s_im,
    const float* __restrict__ x_re,
    const float* __restrict__ x_im,
    const int*   __restrict__ iv,
    const int*   __restrict__ jv,
    float* __restrict__ out)
{
    const int gtid = blockIdx.x * blockDim.x + threadIdx.x;

    // Third output: (j + i) as float, T elements at offset 2*N.
    if (gtid < T_DIM) {
        out[2 * N + gtid] = (float)(jv[gtid] + iv[gtid]);
    }

    // Per-thread invariants: trip stride is 512 full t-planes, so (m, c4)
    // never change across trips; only t advances by T_STEP.
    const int c4 = (gtid & 15) << 2;       // ctx offset of this float4
    const int m  = (gtid >> 4) & 63;       // trace index
    const int t0 = gtid >> 10;             // starting t (0..511)

    const float am = fabsf(a[m]);
    const f32x4 bv = *reinterpret_cast<const f32x4*>(b + c4);

    // 4 super-iterations x 2 trips: 8 stream loads issued per batch, pinned
    // in flight by a data-dependent asm fence before any consumption.
    #pragma unroll
    for (int s = 0; s < TRIPS / 2; ++s) {
        const int baseA = (gtid + (2 * s)     * STRIDE) << 2;
        const int baseB = (gtid + (2 * s + 1) * STRIDE) << 2;
        float tjA = (float)jv[t0 + (2 * s)     * T_STEP];
        float tjB = (float)jv[t0 + (2 * s + 1) * T_STEP];

        f32x4 srA = *reinterpret_cast<const f32x4*>(s_re + baseA);
        f32x4 siA = *reinterpret_cast<const f32x4*>(s_im + baseA);
        f32x4 xrA = *reinterpret_cast<const f32x4*>(x_re + baseA);
        f32x4 xiA = *reinterpret_cast<const f32x4*>(x_im + baseA);
        f32x4 srB = *reinterpret_cast<const f32x4*>(s_re + baseB);
        f32x4 siB = *reinterpret_cast<const f32x4*>(s_im + baseB);
        f32x4 xrB = *reinterpret_cast<const f32x4*>(x_re + baseB);
        f32x4 xiB = *reinterpret_cast<const f32x4*>(x_im + baseB);

        // Data-dependent pin: all 8 loads must be issued (and results
        // materialized) before anything below executes; IR passes cannot
        // sink a load across a use of its result.
        asm volatile("" : "+v"(srA), "+v"(siA), "+v"(xrA), "+v"(xiA),
                          "+v"(srB), "+v"(siB), "+v"(xrB), "+v"(xiB),
                          "+v"(tjA), "+v"(tjB));

        {
            const float decay = __expf(-am * tjA);
            f32x4 orv, oiv;
            #pragma unroll
            for (int k = 0; k < 4; ++k) {
                float sn, cs;
                __sincosf(bv[k] * tjA, &sn, &cs);
                const float gre = decay * cs;
                const float gim = decay * sn;
                orv[k] = fmaf(srA[k], gre, fmaf(-siA[k], gim, xrA[k]));
                oiv[k] = fmaf(srA[k], gim, fmaf( siA[k], gre, xiA[k]));
            }
            __builtin_nontemporal_store(orv, reinterpret_cast<f32x4*>(out + baseA));
            __builtin_nontemporal_store(oiv, reinterpret_cast<f32x4*>(out + N + baseA));
        }
        {
            const float decay = __expf(-am * tjB);
            f32x4 orv, oiv;
            #pragma unroll
            for (int k = 0; k < 4; ++k) {
                float sn, cs;
                __sincosf(bv[k] * tjB, &sn, &cs);
                const float gre = decay * cs;
                const float gim = decay * sn;
                orv[k] = fmaf(srB[k], gre, fmaf(-siB[k], gim, xrB[k]));
                oiv[k] = fmaf(srB[k], gim, fmaf( siB[k], gre, xiB[k]));
            }
            __builtin_nontemporal_store(orv, reinterpret_cast<f32x4*>(out + baseB));
            __builtin_nontemporal_store(oiv, reinterpret_cast<f32x4*>(out + N + baseB));
        }
    }
}

extern "C" void kernel_launch(void* const* d_in, const int* in_sizes, int n_in,
                              void* d_out, int out_size, void* d_ws, size_t ws_size,
                              hipStream_t stream) {
    const float* a    = (const float*)d_in[0];
    const float* b    = (const float*)d_in[1];
    const float* s_re = (const float*)d_in[2];
    const float* s_im = (const float*)d_in[3];
    const float* x_re = (const float*)d_in[4];
    const float* x_im = (const float*)d_in[5];
    const int*   iv   = (const int*)d_in[6];
    const int*   jv   = (const int*)d_in[7];
    float* out = (float*)d_out;

    ffm_kernel<<<GRID, BLOCK, 0, stream>>>(a, b, s_re, s_im, x_re, x_im, iv, jv, out);
}